// Round 14
// baseline (346.227 us; speedup 1.0000x reference)
//
#include <hip/hip_runtime.h>
#include <hip/hip_bf16.h>

// B=4, N=4096 -> T=16384 tokens, D=1024, H=4096, OUT=1024, 4 nested experts.
#define T_TOK 16384
#define DMODEL 1024
#define HDIM 4096
#define OUTD 1024

typedef __attribute__((ext_vector_type(8))) short short8_t;  // 8 x bf16
typedef __attribute__((ext_vector_type(4))) float f32x4;     // MFMA acc

// ---- ws layout ----
// [0] counts[4] | [128] list[4*16384]
// [1MB] xc (<=32MB) | [34MB] w1bf (8MB) | [43MB] w2bf (8MB) | [52MB] hbuf (~63MB)
#define WS_COUNTS_OFF 0
#define WS_LIST_OFF 128
#define WS_XC_OFF   ((size_t)1 << 20)
#define WS_W1BF_OFF ((size_t)34 << 20)
#define WS_W2BF_OFF ((size_t)43 << 20)
#define WS_HBUF_OFF ((size_t)52 << 20)

#define W1N (HDIM * DMODEL)
#define W2N (OUTD * HDIM)

__device__ __forceinline__ short f2bf(float f) {
    union { float f; unsigned u; } x; x.f = f;
    unsigned r = x.u + 0x7FFFu + ((x.u >> 16) & 1u);  // RNE
    return (short)(r >> 16);
}

// gelu(v) = 0.5 v (1 + erf(v/sqrt(2))); erf via Abramowitz-Stegun 7.1.26,
// |err| <= 1.5e-7, branchless.
__device__ __forceinline__ float gelu_fast(float v) {
    float z = fabsf(v) * 0.7071067811865476f;
    float t = __builtin_amdgcn_rcpf(fmaf(0.3275911f, z, 1.0f));
    float poly = t * fmaf(t, fmaf(t, fmaf(t, fmaf(t, 1.061405429f, -1.453152027f),
                                          1.421413741f), -0.284496736f),
                          0.254829592f);
    float e = fmaf(-poly, __expf(-z * z), 1.0f);   // erf(z), z >= 0
    float erfv = copysignf(e, v);
    return 0.5f * v * (1.0f + erfv);
}

__device__ __forceinline__ void conv8(const float* __restrict__ s, short* __restrict__ d) {
    const float4* s4 = (const float4*)s;
    float4 f0 = s4[0], f1 = s4[1];
    short8_t v;
    v[0] = f2bf(f0.x); v[1] = f2bf(f0.y); v[2] = f2bf(f0.z); v[3] = f2bf(f0.w);
    v[4] = f2bf(f1.x); v[5] = f2bf(f1.y); v[6] = f2bf(f1.z); v[7] = f2bf(f1.w);
    *(short8_t*)d = v;
}

__device__ __forceinline__ void gl_lds16(const short* g, short* lds) {
    __builtin_amdgcn_global_load_lds(
        (const __attribute__((address_space(1))) void*)g,
        (__attribute__((address_space(3))) void*)lds, 16, 0, 0);
}

// prefix bases from counts (4-iter scalar loop; counts L2-hit)
__device__ __forceinline__ void bases_for(const int* __restrict__ counts, int e,
                                          unsigned long long* hb,
                                          unsigned long long* xb) {
    unsigned long long h = 0, x = 0;
    for (int i = 0; i < e; ++i) {
        unsigned long long c = (unsigned long long)counts[i];
        int din = 128 << i;
        x += c * (unsigned long long)din;
        h += c * (unsigned long long)(din * 4);
    }
    *hb = h; *xb = x;
}

__global__ void k_build(const int* __restrict__ mask, int* counts, int* list) {
    __shared__ int hcnt[4], hb[4], hpos[4];
    int tid = threadIdx.x;
    if (tid < 4) hcnt[tid] = 0;
    __syncthreads();
    int t = blockIdx.x * 256 + tid;
    int e = mask[t] & 3;
    atomicAdd(&hcnt[e], 1);
    __syncthreads();
    if (tid < 4) { hb[tid] = atomicAdd(&counts[tid], hcnt[tid]); hpos[tid] = 0; }
    __syncthreads();
    int p = atomicAdd(&hpos[e], 1);
    list[e * T_TOK + hb[e] + p] = t;
}

// Fused gather + weight-convert (one dispatch instead of two):
// blockIdx.y 0..3: xc[e][i,:d_in] = bf16(x[list[e][i],:d_in])   (needs build)
// blockIdx.y 4   : w1bf/w2bf = bf16(w1/w2)                      (independent)
__global__ void k_xgc(const float* __restrict__ x, const int* __restrict__ counts,
                      const int* __restrict__ list, short* __restrict__ xc,
                      const float* __restrict__ w1, const float* __restrict__ w2,
                      short* __restrict__ w1bf, short* __restrict__ w2bf) {
    if (blockIdx.y == 4) {
        for (size_t elem = ((size_t)blockIdx.x * 256 + threadIdx.x) * 8;
             elem < (size_t)(W1N + W2N); elem += (size_t)gridDim.x * 256 * 8) {
            if (elem < (size_t)W1N) {
                conv8(w1 + elem, w1bf + elem);
            } else {
                size_t o = elem - W1N; conv8(w2 + o, w2bf + o);
            }
        }
        return;
    }
    const int e = blockIdx.y;
    const int d_in = 128 << e;
    const int cnt = counts[e];
    unsigned long long hbD, xb;
    bases_for(counts, e, &hbD, &xb);
    const size_t nel = (size_t)cnt * d_in;
    const int* lst = list + e * T_TOK;
    short* dst = xc + xb;
    for (size_t idx = ((size_t)blockIdx.x * 256 + threadIdx.x) * 8; idx < nel;
         idx += (size_t)gridDim.x * 256 * 8) {
        int row = (int)(idx >> (7 + e));
        int col = (int)(idx & (d_in - 1));
        int tok = lst[row];
        conv8(x + (size_t)tok * DMODEL + col, dst + idx);
    }
}

// ---------------------------------------------------------------------------
// Pass 1: h = gelu(xc @ W1[:d_hid, :d_in]^T + b1)  (bf16, compact rows)
// R11-LOCKED (best: ~80us): 128m x 128n tile, 512 threads (8 waves), per-wave
// shape = proven 32m x 64n / acc 2x4 / 16 MFMA per barrier. Single 32KB LDS,
// 2-barrier K-loop, XCD panel map. Supply: e3 = 128 blocks/XCD = 4/CU.
// ---------------------------------------------------------------------------
__global__ __launch_bounds__(512) void k_pass1(
    const short* __restrict__ xc, const short* __restrict__ w1bf,
    const float* __restrict__ b1, const int* __restrict__ counts,
    short* __restrict__ hbuf)
{
    const int d = blockIdx.x;        // 0..2047
    const int xcd = d & 7;
    const int slot = d >> 3;         // 0..255
    const int g = slot >> 5;         // panel group 0..7
    const int bx = slot & 31;        // m-block within panel
    int e, nt;
    if (g < 4)       { e = 3; nt = xcd * 4 + g; }
    else if (g < 6)  { e = 2; nt = xcd * 2 + (g - 4); }
    else if (g == 6) { e = 1; nt = xcd; }
    else             { if (xcd >= 4) return; e = 0; nt = xcd; }
    const int d_in = 128 << e;
    const int d_hid = d_in * 4;
    const int n0 = nt * 128;
    const int cnt = counts[e];
    unsigned long long hb, xb;
    bases_for(counts, e, &hb, &xb);
    const short* xe = xc + xb;

    __shared__ short Ab[128 * 64];   // 16KB
    __shared__ short Bb[128 * 64];   // 16KB

    const int tid = threadIdx.x;
    const int lane = tid & 63;
    const int w = tid >> 6;          // 0..7
    const int l3 = lane >> 3;        // 0..7
    const int ch = lane & 7;
    const int wm = (w & 3) * 32;     // 4-way m-split over 128 rows
    const int wn = (w >> 2) * 64;    // 2-way n-split over 128 cols

    for (int m0 = bx * 128; m0 < cnt; m0 += 32 * 128) {
        // A staging rows for this thread's 2 rounds (clamped)
        int rA[2];
#pragma unroll
        for (int j = 0; j < 2; ++j) {
            int rr = m0 + j * 64 + w * 8 + l3;
            rA[j] = (rr >= cnt) ? (cnt - 1) : rr;
        }

        f32x4 acc[2][4];
#pragma unroll
        for (int i = 0; i < 2; ++i)
#pragma unroll
            for (int j = 0; j < 4; ++j)
                acc[i][j] = (f32x4){0.f, 0.f, 0.f, 0.f};

        for (int k0 = 0; k0 < d_in; k0 += 64) {
#pragma unroll
            for (int j = 0; j < 2; ++j) {
                int r = j * 64 + w * 8 + l3;
                gl_lds16(xe + (size_t)rA[j] * d_in + k0 + ((ch ^ (r & 7)) << 3),
                         &Ab[(j * 64 + w * 8) * 64]);
            }
#pragma unroll
            for (int j = 0; j < 2; ++j) {
                int r = j * 64 + w * 8 + l3;
                gl_lds16(w1bf + (size_t)(n0 + r) * DMODEL + k0 + ((ch ^ (r & 7)) << 3),
                         &Bb[(j * 64 + w * 8) * 64]);
            }
            __syncthreads();
#pragma unroll
            for (int kk = 0; kk < 2; ++kk) {
                short8_t af[2], bfr[4];
                const int q = (lane >> 4) + kk * 4;
#pragma unroll
                for (int mt = 0; mt < 2; ++mt) {
                    int row = wm + mt * 16 + (lane & 15);
                    af[mt] = *(const short8_t*)&Ab[((row << 3) | (q ^ (row & 7))) << 3];
                }
#pragma unroll
                for (int ntn = 0; ntn < 4; ++ntn) {
                    int row = wn + ntn * 16 + (lane & 15);
                    bfr[ntn] = *(const short8_t*)&Bb[((row << 3) | (q ^ (row & 7))) << 3];
                }
#pragma unroll
                for (int mt = 0; mt < 2; ++mt)
#pragma unroll
                    for (int ntn = 0; ntn < 4; ++ntn)
                        acc[mt][ntn] = __builtin_amdgcn_mfma_f32_16x16x32_bf16(
                            af[mt], bfr[ntn], acc[mt][ntn], 0, 0, 0);
            }
            __syncthreads();
        }

        const int cl = lane & 15;
        const int qr = lane >> 4;
#pragma unroll
        for (int ntn = 0; ntn < 4; ++ntn) {
            int col = n0 + wn + ntn * 16 + cl;
            float bias = b1[col];
#pragma unroll
            for (int mt = 0; mt < 2; ++mt) {
#pragma unroll
                for (int r = 0; r < 4; ++r) {
                    int row = wm + mt * 16 + qr * 4 + r;
                    if (m0 + row < cnt) {
                        float v = acc[mt][ntn][r] + bias;
                        hbuf[hb + (unsigned long long)(m0 + row) * d_hid + col] =
                            f2bf(gelu_fast(v));
                    }
                }
            }
        }
    }
}

// ---------------------------------------------------------------------------
// Pass 2: y[tok, :d_out] = h @ W2[:d_out, :d_hid]^T + b2  (scatter, fp32)
// Compute core LOCKED (R11: 128m x 128n, 512 thr, counted-vmcnt(4) dbuf 64KB).
// NEW: INVERTED XCD mapping — each XCD owns m-blocks mi = xcd (mod 8) and
// iterates all n-panels. A footprint per XCD = ~4 m-blocks x 1MB -> hbuf A
// becomes L2-RESIDENT (each A row read by 8 n-panel blocks, 7/8 from L2);
// B (8.4MB unique, read by all XCDs) is L3-resident. Staged bytes unchanged;
// far-memory stream shifts A:L3/HBM(33.5MB) -> B:L3(32MB); HBM fetch should
// drop toward the ~75MB unique footprint (was 180MB with panel mapping).
// Also balances e2/e1/e0 across all 8 XCDs (old map idled xcd7).
// Grid 512 blocks: slot 0..31 e3 | 32..47 e2 | 48..55 e1 | 56..59 e0 |
// 60..63 zero-fill of y pad cols.
// ---------------------------------------------------------------------------
__global__ __launch_bounds__(512) void k_pass2(
    const short* __restrict__ hbuf, const short* __restrict__ w2bf,
    const float* __restrict__ b2, const int* __restrict__ counts,
    const int* __restrict__ list, float* __restrict__ y)
{
    const int d = blockIdx.x;        // 0..511
    const int xcd = d & 7;
    const int slot = d >> 3;         // 0..63
    if (slot >= 60) {
        // flattened zero-fill of pad region: 128-row chunks, 32 workers
        const int z = xcd * 4 + (slot - 60);      // 0..31
        const int ch2 = (counts[2] + 127) >> 7, ch1 = (counts[1] + 127) >> 7,
                  ch0 = (counts[0] + 127) >> 7;
        const int n2 = ch2 * 4, n1 = ch1 * 6, n0c = ch0 * 7;
        const int rt = threadIdx.x >> 2;          // row-in-chunk 0..127
        const int cq = (threadIdx.x & 3) * 32;    // col quarter
        const float4 z4 = (float4){0.f, 0.f, 0.f, 0.f};
        for (int c = z; c < n2 + n1 + n0c; c += 32) {
            int e, nt, mi, cc = c;
            if (cc < n2)            { e = 2; nt = 4 + cc / ch2; mi = cc % ch2; }
            else { cc -= n2;
                if (cc < n1)        { e = 1; nt = 2 + cc / ch1; mi = cc % ch1; }
                else { cc -= n1;      e = 0; nt = 1 + cc / ch0; mi = cc % ch0; } }
            const int cnt = counts[e];
            int row = mi * 128 + rt;
            if (row < cnt) {
                float* dst = y + (size_t)list[e * T_TOK + row] * OUTD + nt * 128 + cq;
#pragma unroll
                for (int i = 0; i < 8; ++i) *(float4*)(dst + i * 4) = z4;
            }
        }
        return;
    }
    int e, bxs, ni;
    if (slot < 32)      { e = 3; bxs = slot >> 3; ni = slot & 7; }
    else if (slot < 48) { int s = slot - 32; e = 2; bxs = s >> 2; ni = s & 3; }
    else if (slot < 56) { int s = slot - 48; e = 1; bxs = s >> 1; ni = s & 1; }
    else                { e = 0; bxs = slot - 56; ni = 0; }
    const int d_in = 128 << e;
    const int d_hid = d_in * 4;
    const int n0 = ni * 128;
    const int cnt = counts[e];
    const int* lst = list + e * T_TOK;
    unsigned long long hb, xb;
    bases_for(counts, e, &hb, &xb);

    __shared__ short Ab[2 * 128 * 64];   // 32KB
    __shared__ short Bb[2 * 128 * 64];   // 32KB

    const int tid = threadIdx.x;
    const int lane = tid & 63;
    const int w = tid >> 6;          // 0..7
    const int l3 = lane >> 3;
    const int ch = lane & 7;
    const int wm = (w & 3) * 32;     // 4-way m-split over 128 rows
    const int wn = (w >> 2) * 64;    // 2-way n-split over 128 cols

#define P2_STAGE(kn, b) do {                                                   \
    _Pragma("unroll") for (int j = 0; j < 2; ++j) {                            \
        int r = j * 64 + w * 8 + l3;                                           \
        gl_lds16(hbuf + hb + (size_t)rA[j] * d_hid + (kn) + ((ch ^ (r & 7)) << 3), \
                 &Ab[(b) * 8192 + (j * 64 + w * 8) * 64]); }                   \
    _Pragma("unroll") for (int j = 0; j < 2; ++j) {                            \
        int r = j * 64 + w * 8 + l3;                                           \
        gl_lds16(w2bf + (size_t)(n0 + r) * HDIM + (kn) + ((ch ^ (r & 7)) << 3), \
                 &Bb[(b) * 8192 + (j * 64 + w * 8) * 64]); }                   \
} while (0)

    // m-blocks mi = bxs*8 + xcd (mi % 8 == xcd), stride 32 blocks for tails
    for (int m0 = (bxs * 8 + xcd) * 128; m0 < cnt; m0 += 32 * 128) {
        int rA[2];
#pragma unroll
        for (int j = 0; j < 2; ++j) {
            int rr = m0 + j * 64 + w * 8 + l3;
            rA[j] = (rr >= cnt) ? (cnt - 1) : rr;
        }

        f32x4 acc[2][4];
#pragma unroll
        for (int i = 0; i < 2; ++i)
#pragma unroll
            for (int j = 0; j < 4; ++j)
                acc[i][j] = (f32x4){0.f, 0.f, 0.f, 0.f};

        const int ks = d_hid >> 6;       // 8/16/32/64 (always even)
        P2_STAGE(0, 0);                  // prologue: kt=0 -> buf0
        for (int kt = 0; kt < ks; ++kt) {
            const int p = kt & 1;
            __builtin_amdgcn_s_barrier();                    // B1
            if (kt + 1 < ks) {
                P2_STAGE((kt + 1) << 6, 1 - p);
                asm volatile("s_waitcnt vmcnt(4)" ::: "memory");
            } else {
                asm volatile("s_waitcnt vmcnt(0)" ::: "memory");
            }
            __builtin_amdgcn_s_barrier();                    // B2
            const short* Ap = &Ab[p * 8192];
            const short* Bp = &Bb[p * 8192];
#pragma unroll
            for (int kk = 0; kk < 2; ++kk) {
                short8_t af[2], bfr[4];
                const int q = (lane >> 4) + kk * 4;
#pragma unroll
                for (int mt = 0; mt < 2; ++mt) {
                    int row = wm + mt * 16 + (lane & 15);
                    af[mt] = *(const short8_t*)&Ap[((row << 3) | (q ^ (row & 7))) << 3];
                }
#pragma unroll
                for (int ntn = 0; ntn < 4; ++ntn) {
                    int row = wn + ntn * 16 + (lane & 15);
                    bfr[ntn] = *(const short8_t*)&Bp[((row << 3) | (q ^ (row & 7))) << 3];
                }
#pragma unroll
                for (int mt = 0; mt < 2; ++mt)
#pragma unroll
                    for (int ntn = 0; ntn < 4; ++ntn)
                        acc[mt][ntn] = __builtin_amdgcn_mfma_f32_16x16x32_bf16(
                            af[mt], bfr[ntn], acc[mt][ntn], 0, 0, 0);
            }
        }

        const int cl = lane & 15;
        const int qr = lane >> 4;
#pragma unroll
        for (int ntn = 0; ntn < 4; ++ntn) {
            int col = n0 + wn + ntn * 16 + cl;
            float bias = b2[col];
#pragma unroll
            for (int mt = 0; mt < 2; ++mt) {
#pragma unroll
                for (int r = 0; r < 4; ++r) {
                    int row = wm + mt * 16 + qr * 4 + r;
                    if (m0 + row < cnt) {
                        int tok = lst[m0 + row];
                        y[(size_t)tok * OUTD + col] = acc[mt][ntn][r] + bias;
                    }
                }
            }
        }
    }
#undef P2_STAGE
}

extern "C" void kernel_launch(void* const* d_in, const int* in_sizes, int n_in,
                              void* d_out, int out_size, void* d_ws, size_t ws_size,
                              hipStream_t stream) {
    const float* x  = (const float*)d_in[0];
    const int* mask = (const int*)d_in[1];
    const float* w1 = (const float*)d_in[2];
    const float* b1 = (const float*)d_in[3];
    const float* w2 = (const float*)d_in[4];
    const float* b2 = (const float*)d_in[5];
    float* y = (float*)d_out;

    char* ws = (char*)d_ws;
    int* counts = (int*)(ws + WS_COUNTS_OFF);
    int* list = (int*)(ws + WS_LIST_OFF);
    short* xc   = (short*)(ws + WS_XC_OFF);
    short* w1bf = (short*)(ws + WS_W1BF_OFF);
    short* w2bf = (short*)(ws + WS_W2BF_OFF);
    short* hbuf = (short*)(ws + WS_HBUF_OFF);

    hipMemsetAsync(counts, 0, 4 * sizeof(int), stream);
    k_build<<<T_TOK / 256, 256, 0, stream>>>(mask, counts, list);
    k_xgc<<<dim3(256, 5), 256, 0, stream>>>(x, counts, list, xc, w1, w2, w1bf, w2bf);
    k_pass1<<<2048, 512, 0, stream>>>(xc, w1bf, b1, counts, hbuf);
    k_pass2<<<512, 512, 0, stream>>>(hbuf, w2bf, b2, counts, list, y);
}

// Round 15
// 330.827 us; speedup vs baseline: 1.0465x; 1.0465x over previous
//
#include <hip/hip_runtime.h>
#include <hip/hip_bf16.h>

// B=4, N=4096 -> T=16384 tokens, D=1024, H=4096, OUT=1024, 4 nested experts.
#define T_TOK 16384
#define DMODEL 1024
#define HDIM 4096
#define OUTD 1024

typedef __attribute__((ext_vector_type(8))) short short8_t;  // 8 x bf16
typedef __attribute__((ext_vector_type(4))) float f32x4;     // MFMA acc

// ---- ws layout ----
// [0] counts[4] | [128] list[4*16384]
// [1MB] xc (<=32MB) | [34MB] w1bf (8MB) | [43MB] w2bf (8MB) | [52MB] hbuf (~63MB)
#define WS_COUNTS_OFF 0
#define WS_LIST_OFF 128
#define WS_XC_OFF   ((size_t)1 << 20)
#define WS_W1BF_OFF ((size_t)34 << 20)
#define WS_W2BF_OFF ((size_t)43 << 20)
#define WS_HBUF_OFF ((size_t)52 << 20)

#define W1N (HDIM * DMODEL)
#define W2N (OUTD * HDIM)

__device__ __forceinline__ short f2bf(float f) {
    union { float f; unsigned u; } x; x.f = f;
    unsigned r = x.u + 0x7FFFu + ((x.u >> 16) & 1u);  // RNE
    return (short)(r >> 16);
}

// gelu(v) = 0.5 v (1 + erf(v/sqrt(2))); erf via Abramowitz-Stegun 7.1.26,
// |err| <= 1.5e-7, branchless.
__device__ __forceinline__ float gelu_fast(float v) {
    float z = fabsf(v) * 0.7071067811865476f;
    float t = __builtin_amdgcn_rcpf(fmaf(0.3275911f, z, 1.0f));
    float poly = t * fmaf(t, fmaf(t, fmaf(t, fmaf(t, 1.061405429f, -1.453152027f),
                                          1.421413741f), -0.284496736f),
                          0.254829592f);
    float e = fmaf(-poly, __expf(-z * z), 1.0f);   // erf(z), z >= 0
    float erfv = copysignf(e, v);
    return 0.5f * v * (1.0f + erfv);
}

__device__ __forceinline__ void conv8(const float* __restrict__ s, short* __restrict__ d) {
    const float4* s4 = (const float4*)s;
    float4 f0 = s4[0], f1 = s4[1];
    short8_t v;
    v[0] = f2bf(f0.x); v[1] = f2bf(f0.y); v[2] = f2bf(f0.z); v[3] = f2bf(f0.w);
    v[4] = f2bf(f1.x); v[5] = f2bf(f1.y); v[6] = f2bf(f1.z); v[7] = f2bf(f1.w);
    *(short8_t*)d = v;
}

__device__ __forceinline__ void gl_lds16(const short* g, short* lds) {
    __builtin_amdgcn_global_load_lds(
        (const __attribute__((address_space(1))) void*)g,
        (__attribute__((address_space(3))) void*)lds, 16, 0, 0);
}

// prefix bases from counts (4-iter scalar loop; counts L2-hit)
__device__ __forceinline__ void bases_for(const int* __restrict__ counts, int e,
                                          unsigned long long* hb,
                                          unsigned long long* xb) {
    unsigned long long h = 0, x = 0;
    for (int i = 0; i < e; ++i) {
        unsigned long long c = (unsigned long long)counts[i];
        int din = 128 << i;
        x += c * (unsigned long long)din;
        h += c * (unsigned long long)(din * 4);
    }
    *hb = h; *xb = x;
}

__global__ void k_build(const int* __restrict__ mask, int* counts, int* list) {
    __shared__ int hcnt[4], hb[4], hpos[4];
    int tid = threadIdx.x;
    if (tid < 4) hcnt[tid] = 0;
    __syncthreads();
    int t = blockIdx.x * 256 + tid;
    int e = mask[t] & 3;
    atomicAdd(&hcnt[e], 1);
    __syncthreads();
    if (tid < 4) { hb[tid] = atomicAdd(&counts[tid], hcnt[tid]); hpos[tid] = 0; }
    __syncthreads();
    int p = atomicAdd(&hpos[e], 1);
    list[e * T_TOK + hb[e] + p] = t;
}

// Fused gather + weight-convert (one dispatch instead of two):
// blockIdx.y 0..3: xc[e][i,:d_in] = bf16(x[list[e][i],:d_in])   (needs build)
// blockIdx.y 4   : w1bf/w2bf = bf16(w1/w2)                      (independent)
__global__ void k_xgc(const float* __restrict__ x, const int* __restrict__ counts,
                      const int* __restrict__ list, short* __restrict__ xc,
                      const float* __restrict__ w1, const float* __restrict__ w2,
                      short* __restrict__ w1bf, short* __restrict__ w2bf) {
    if (blockIdx.y == 4) {
        for (size_t elem = ((size_t)blockIdx.x * 256 + threadIdx.x) * 8;
             elem < (size_t)(W1N + W2N); elem += (size_t)gridDim.x * 256 * 8) {
            if (elem < (size_t)W1N) {
                conv8(w1 + elem, w1bf + elem);
            } else {
                size_t o = elem - W1N; conv8(w2 + o, w2bf + o);
            }
        }
        return;
    }
    const int e = blockIdx.y;
    const int d_in = 128 << e;
    const int cnt = counts[e];
    unsigned long long hbD, xb;
    bases_for(counts, e, &hbD, &xb);
    const size_t nel = (size_t)cnt * d_in;
    const int* lst = list + e * T_TOK;
    short* dst = xc + xb;
    for (size_t idx = ((size_t)blockIdx.x * 256 + threadIdx.x) * 8; idx < nel;
         idx += (size_t)gridDim.x * 256 * 8) {
        int row = (int)(idx >> (7 + e));
        int col = (int)(idx & (d_in - 1));
        int tok = lst[row];
        conv8(x + (size_t)tok * DMODEL + col, dst + idx);
    }
}

// ---------------------------------------------------------------------------
// Pass 1: h = gelu(xc @ W1[:d_hid, :d_in]^T + b1)  (bf16, compact rows)
// NEW: 128m x 256n tile, 512 threads (8 waves: 4 m-splits x 2 n-splits;
// per-wave 32m x 128n, acc 2x8, 32 MFMA per barrier-pair). A re-staging
// halves (A-part = M*K*2*(N/BN): e3 268 -> 134MB; total -25%). Single 48KB
// LDS (A 16KB + B 32KB), 2-barrier K-loop. Supply: e3 = 16 n-panels x 32
// m-blocks = 512 blocks = 2/CU (same regime where R11-pass2 won).
// XCD map: g0,g1 = e3 (2 panels/XCD); g2 = e2 (1/XCD); g3 = e1 (xcd<4) /
// e0 (xcd 4,5).
// ---------------------------------------------------------------------------
__global__ __launch_bounds__(512) void k_pass1(
    const short* __restrict__ xc, const short* __restrict__ w1bf,
    const float* __restrict__ b1, const int* __restrict__ counts,
    short* __restrict__ hbuf)
{
    const int d = blockIdx.x;        // 0..1023
    const int xcd = d & 7;
    const int slot = d >> 3;         // 0..127
    const int g = slot >> 5;         // panel group 0..3
    const int bx = slot & 31;        // m-block within panel
    int e, nt;
    if (g < 2)       { e = 3; nt = xcd * 2 + g; }
    else if (g == 2) { e = 2; nt = xcd; }
    else {
        if (xcd < 4)      { e = 1; nt = xcd; }
        else if (xcd < 6) { e = 0; nt = xcd - 4; }
        else return;
    }
    const int d_in = 128 << e;
    const int d_hid = d_in * 4;
    const int n0 = nt * 256;
    const int cnt = counts[e];
    unsigned long long hb, xb;
    bases_for(counts, e, &hb, &xb);
    const short* xe = xc + xb;

    __shared__ short Ab[128 * 64];   // 16KB
    __shared__ short Bb[256 * 64];   // 32KB

    const int tid = threadIdx.x;
    const int lane = tid & 63;
    const int w = tid >> 6;          // 0..7
    const int l3 = lane >> 3;        // 0..7
    const int ch = lane & 7;
    const int wm = (w & 3) * 32;     // 4-way m-split over 128 rows
    const int wn = (w >> 2) * 128;   // 2-way n-split over 256 cols

    for (int m0 = bx * 128; m0 < cnt; m0 += 32 * 128) {
        // A staging rows for this thread's 2 rounds (clamped)
        int rA[2];
#pragma unroll
        for (int j = 0; j < 2; ++j) {
            int rr = m0 + j * 64 + w * 8 + l3;
            rA[j] = (rr >= cnt) ? (cnt - 1) : rr;
        }

        f32x4 acc[2][8];
#pragma unroll
        for (int i = 0; i < 2; ++i)
#pragma unroll
            for (int j = 0; j < 8; ++j)
                acc[i][j] = (f32x4){0.f, 0.f, 0.f, 0.f};

        for (int k0 = 0; k0 < d_in; k0 += 64) {
#pragma unroll
            for (int j = 0; j < 2; ++j) {
                int r = j * 64 + w * 8 + l3;
                gl_lds16(xe + (size_t)rA[j] * d_in + k0 + ((ch ^ (r & 7)) << 3),
                         &Ab[(j * 64 + w * 8) * 64]);
            }
#pragma unroll
            for (int j = 0; j < 4; ++j) {
                int r = j * 64 + w * 8 + l3;
                gl_lds16(w1bf + (size_t)(n0 + r) * DMODEL + k0 + ((ch ^ (r & 7)) << 3),
                         &Bb[(j * 64 + w * 8) * 64]);
            }
            __syncthreads();
#pragma unroll
            for (int kk = 0; kk < 2; ++kk) {
                short8_t af[2], bfr[8];
                const int q = (lane >> 4) + kk * 4;
#pragma unroll
                for (int mt = 0; mt < 2; ++mt) {
                    int row = wm + mt * 16 + (lane & 15);
                    af[mt] = *(const short8_t*)&Ab[((row << 3) | (q ^ (row & 7))) << 3];
                }
#pragma unroll
                for (int ntn = 0; ntn < 8; ++ntn) {
                    int row = wn + ntn * 16 + (lane & 15);
                    bfr[ntn] = *(const short8_t*)&Bb[((row << 3) | (q ^ (row & 7))) << 3];
                }
#pragma unroll
                for (int mt = 0; mt < 2; ++mt)
#pragma unroll
                    for (int ntn = 0; ntn < 8; ++ntn)
                        acc[mt][ntn] = __builtin_amdgcn_mfma_f32_16x16x32_bf16(
                            af[mt], bfr[ntn], acc[mt][ntn], 0, 0, 0);
            }
            __syncthreads();
        }

        const int cl = lane & 15;
        const int qr = lane >> 4;
#pragma unroll
        for (int ntn = 0; ntn < 8; ++ntn) {
            int col = n0 + wn + ntn * 16 + cl;
            float bias = b1[col];
#pragma unroll
            for (int mt = 0; mt < 2; ++mt) {
#pragma unroll
                for (int r = 0; r < 4; ++r) {
                    int row = wm + mt * 16 + qr * 4 + r;
                    if (m0 + row < cnt) {
                        float v = acc[mt][ntn][r] + bias;
                        hbuf[hb + (unsigned long long)(m0 + row) * d_hid + col] =
                            f2bf(gelu_fast(v));
                    }
                }
            }
        }
    }
}

// ---------------------------------------------------------------------------
// Pass 2: y[tok, :d_out] = h @ W2[:d_out, :d_hid]^T + b2  (scatter, fp32)
// R13-BENCHED EXACT (banked best, 92us): 128m x 128n, 512 thr, counted-
// vmcnt(4) dbuf 64KB, XCD PANEL map. R14's inverted map cut FETCH 180->82MB
// but was time-neutral on compute and its 32-worker zfill tail cost +35us —
// proof the staging-rate wall, not HBM traffic, binds. Reverted.
//   g0: e3 panel nt=xcd | g1: xcd0-3 e2 | xcd4,5 e1 | xcd6 e0 | xcd7 idle
//   g2: flattened zero-fill of y pad cols (128-row chunks, 512 workers)
// ---------------------------------------------------------------------------
__global__ __launch_bounds__(512) void k_pass2(
    const short* __restrict__ hbuf, const short* __restrict__ w2bf,
    const float* __restrict__ b2, const int* __restrict__ counts,
    const int* __restrict__ list, float* __restrict__ y)
{
    const int d = blockIdx.x;        // 0..1535
    const int xcd = d & 7;
    const int slot = d >> 3;         // 0..191
    const int g = slot >> 6;         // 0..2
    const int bx = slot & 63;
    if (g == 2) {
        // flattened zero-fill of pad region: 128-row chunks
        const int z = xcd * 64 + bx;              // 0..511
        const int ch2 = (counts[2] + 127) >> 7, ch1 = (counts[1] + 127) >> 7,
                  ch0 = (counts[0] + 127) >> 7;
        const int n2 = ch2 * 4, n1 = ch1 * 6, n0c = ch0 * 7;
        const int rt = threadIdx.x >> 2;          // row-in-chunk 0..127
        const int cq = (threadIdx.x & 3) * 32;    // col quarter
        const float4 z4 = (float4){0.f, 0.f, 0.f, 0.f};
        for (int c = z; c < n2 + n1 + n0c; c += 512) {
            int e, nt, mi, cc = c;
            if (cc < n2)            { e = 2; nt = 4 + cc / ch2; mi = cc % ch2; }
            else { cc -= n2;
                if (cc < n1)        { e = 1; nt = 2 + cc / ch1; mi = cc % ch1; }
                else { cc -= n1;      e = 0; nt = 1 + cc / ch0; mi = cc % ch0; } }
            const int cnt = counts[e];
            int row = mi * 128 + rt;
            if (row < cnt) {
                float* dst = y + (size_t)list[e * T_TOK + row] * OUTD + nt * 128 + cq;
#pragma unroll
                for (int i = 0; i < 8; ++i) *(float4*)(dst + i * 4) = z4;
            }
        }
        return;
    }
    int e, nt;
    if (g == 0) { e = 3; nt = xcd; }
    else {
        if (xcd < 4)       { e = 2; nt = xcd; }
        else if (xcd < 6)  { e = 1; nt = xcd - 4; }
        else if (xcd == 6) { e = 0; nt = 0; }
        else return;
    }
    const int d_in = 128 << e;
    const int d_hid = d_in * 4;
    const int n0 = nt * 128;
    const int cnt = counts[e];
    const int* lst = list + e * T_TOK;
    unsigned long long hb, xb;
    bases_for(counts, e, &hb, &xb);

    __shared__ short Ab[2 * 128 * 64];   // 32KB
    __shared__ short Bb[2 * 128 * 64];   // 32KB

    const int tid = threadIdx.x;
    const int lane = tid & 63;
    const int w = tid >> 6;          // 0..7
    const int l3 = lane >> 3;
    const int ch = lane & 7;
    const int wm = (w & 3) * 32;     // 4-way m-split over 128 rows
    const int wn = (w >> 2) * 64;    // 2-way n-split over 128 cols

#define P2_STAGE(kn, b) do {                                                   \
    _Pragma("unroll") for (int j = 0; j < 2; ++j) {                            \
        int r = j * 64 + w * 8 + l3;                                           \
        gl_lds16(hbuf + hb + (size_t)rA[j] * d_hid + (kn) + ((ch ^ (r & 7)) << 3), \
                 &Ab[(b) * 8192 + (j * 64 + w * 8) * 64]); }                   \
    _Pragma("unroll") for (int j = 0; j < 2; ++j) {                            \
        int r = j * 64 + w * 8 + l3;                                           \
        gl_lds16(w2bf + (size_t)(n0 + r) * HDIM + (kn) + ((ch ^ (r & 7)) << 3), \
                 &Bb[(b) * 8192 + (j * 64 + w * 8) * 64]); }                   \
} while (0)

    for (int m0 = bx * 128; m0 < cnt; m0 += 64 * 128) {
        int rA[2];
#pragma unroll
        for (int j = 0; j < 2; ++j) {
            int rr = m0 + j * 64 + w * 8 + l3;
            rA[j] = (rr >= cnt) ? (cnt - 1) : rr;
        }

        f32x4 acc[2][4];
#pragma unroll
        for (int i = 0; i < 2; ++i)
#pragma unroll
            for (int j = 0; j < 4; ++j)
                acc[i][j] = (f32x4){0.f, 0.f, 0.f, 0.f};

        const int ks = d_hid >> 6;       // 8/16/32/64 (always even)
        P2_STAGE(0, 0);                  // prologue: kt=0 -> buf0
        for (int kt = 0; kt < ks; ++kt) {
            const int p = kt & 1;
            __builtin_amdgcn_s_barrier();                    // B1
            if (kt + 1 < ks) {
                P2_STAGE((kt + 1) << 6, 1 - p);
                asm volatile("s_waitcnt vmcnt(4)" ::: "memory");
            } else {
                asm volatile("s_waitcnt vmcnt(0)" ::: "memory");
            }
            __builtin_amdgcn_s_barrier();                    // B2
            const short* Ap = &Ab[p * 8192];
            const short* Bp = &Bb[p * 8192];
#pragma unroll
            for (int kk = 0; kk < 2; ++kk) {
                short8_t af[2], bfr[4];
                const int q = (lane >> 4) + kk * 4;
#pragma unroll
                for (int mt = 0; mt < 2; ++mt) {
                    int row = wm + mt * 16 + (lane & 15);
                    af[mt] = *(const short8_t*)&Ap[((row << 3) | (q ^ (row & 7))) << 3];
                }
#pragma unroll
                for (int ntn = 0; ntn < 4; ++ntn) {
                    int row = wn + ntn * 16 + (lane & 15);
                    bfr[ntn] = *(const short8_t*)&Bp[((row << 3) | (q ^ (row & 7))) << 3];
                }
#pragma unroll
                for (int mt = 0; mt < 2; ++mt)
#pragma unroll
                    for (int ntn = 0; ntn < 4; ++ntn)
                        acc[mt][ntn] = __builtin_amdgcn_mfma_f32_16x16x32_bf16(
                            af[mt], bfr[ntn], acc[mt][ntn], 0, 0, 0);
            }
        }

        const int cl = lane & 15;
        const int qr = lane >> 4;
#pragma unroll
        for (int ntn = 0; ntn < 4; ++ntn) {
            int col = n0 + wn + ntn * 16 + cl;
            float bias = b2[col];
#pragma unroll
            for (int mt = 0; mt < 2; ++mt) {
#pragma unroll
                for (int r = 0; r < 4; ++r) {
                    int row = wm + mt * 16 + qr * 4 + r;
                    if (m0 + row < cnt) {
                        int tok = lst[m0 + row];
                        y[(size_t)tok * OUTD + col] = acc[mt][ntn][r] + bias;
                    }
                }
            }
        }
    }
#undef P2_STAGE
}

extern "C" void kernel_launch(void* const* d_in, const int* in_sizes, int n_in,
                              void* d_out, int out_size, void* d_ws, size_t ws_size,
                              hipStream_t stream) {
    const float* x  = (const float*)d_in[0];
    const int* mask = (const int*)d_in[1];
    const float* w1 = (const float*)d_in[2];
    const float* b1 = (const float*)d_in[3];
    const float* w2 = (const float*)d_in[4];
    const float* b2 = (const float*)d_in[5];
    float* y = (float*)d_out;

    char* ws = (char*)d_ws;
    int* counts = (int*)(ws + WS_COUNTS_OFF);
    int* list = (int*)(ws + WS_LIST_OFF);
    short* xc   = (short*)(ws + WS_XC_OFF);
    short* w1bf = (short*)(ws + WS_W1BF_OFF);
    short* w2bf = (short*)(ws + WS_W2BF_OFF);
    short* hbuf = (short*)(ws + WS_HBUF_OFF);

    hipMemsetAsync(counts, 0, 4 * sizeof(int), stream);
    k_build<<<T_TOK / 256, 256, 0, stream>>>(mask, counts, list);
    k_xgc<<<dim3(256, 5), 256, 0, stream>>>(x, counts, list, xc, w1, w2, w1bf, w2bf);
    k_pass1<<<1024, 512, 0, stream>>>(xc, w1bf, b1, counts, hbuf);
    k_pass2<<<1536, 512, 0, stream>>>(hbuf, w2bf, b2, counts, list, y);
}

// Round 16
// 306.577 us; speedup vs baseline: 1.1293x; 1.0791x over previous
//
#include <hip/hip_runtime.h>
#include <hip/hip_bf16.h>

// B=4, N=4096 -> T=16384 tokens, D=1024, H=4096, OUT=1024, 4 nested experts.
#define T_TOK 16384
#define DMODEL 1024
#define HDIM 4096
#define OUTD 1024

typedef __attribute__((ext_vector_type(8))) short short8_t;  // 8 x bf16
typedef __attribute__((ext_vector_type(4))) float f32x4;     // MFMA acc

// ---- ws layout ----
// [0] counts[4] | [128] list[4*16384]
// [1MB] xc (<=32MB) | [34MB] w1bf (8MB) | [43MB] w2bf (8MB) | [52MB] hbuf (~63MB)
#define WS_COUNTS_OFF 0
#define WS_LIST_OFF 128
#define WS_XC_OFF   ((size_t)1 << 20)
#define WS_W1BF_OFF ((size_t)34 << 20)
#define WS_W2BF_OFF ((size_t)43 << 20)
#define WS_HBUF_OFF ((size_t)52 << 20)

#define W1N (HDIM * DMODEL)
#define W2N (OUTD * HDIM)

__device__ __forceinline__ short f2bf(float f) {
    union { float f; unsigned u; } x; x.f = f;
    unsigned r = x.u + 0x7FFFu + ((x.u >> 16) & 1u);  // RNE
    return (short)(r >> 16);
}

// gelu(v) = 0.5 v (1 + erf(v/sqrt(2))); erf via Abramowitz-Stegun 7.1.26,
// |err| <= 1.5e-7, branchless.
__device__ __forceinline__ float gelu_fast(float v) {
    float z = fabsf(v) * 0.7071067811865476f;
    float t = __builtin_amdgcn_rcpf(fmaf(0.3275911f, z, 1.0f));
    float poly = t * fmaf(t, fmaf(t, fmaf(t, fmaf(t, 1.061405429f, -1.453152027f),
                                          1.421413741f), -0.284496736f),
                          0.254829592f);
    float e = fmaf(-poly, __expf(-z * z), 1.0f);   // erf(z), z >= 0
    float erfv = copysignf(e, v);
    return 0.5f * v * (1.0f + erfv);
}

__device__ __forceinline__ void conv8(const float* __restrict__ s, short* __restrict__ d) {
    const float4* s4 = (const float4*)s;
    float4 f0 = s4[0], f1 = s4[1];
    short8_t v;
    v[0] = f2bf(f0.x); v[1] = f2bf(f0.y); v[2] = f2bf(f0.z); v[3] = f2bf(f0.w);
    v[4] = f2bf(f1.x); v[5] = f2bf(f1.y); v[6] = f2bf(f1.z); v[7] = f2bf(f1.w);
    *(short8_t*)d = v;
}

__device__ __forceinline__ void gl_lds16(const short* g, short* lds) {
    __builtin_amdgcn_global_load_lds(
        (const __attribute__((address_space(1))) void*)g,
        (__attribute__((address_space(3))) void*)lds, 16, 0, 0);
}

// prefix bases from counts (4-iter scalar loop; counts L2-hit)
__device__ __forceinline__ void bases_for(const int* __restrict__ counts, int e,
                                          unsigned long long* hb,
                                          unsigned long long* xb) {
    unsigned long long h = 0, x = 0;
    for (int i = 0; i < e; ++i) {
        unsigned long long c = (unsigned long long)counts[i];
        int din = 128 << i;
        x += c * (unsigned long long)din;
        h += c * (unsigned long long)(din * 4);
    }
    *hb = h; *xb = x;
}

__global__ void k_build(const int* __restrict__ mask, int* counts, int* list) {
    __shared__ int hcnt[4], hb[4], hpos[4];
    int tid = threadIdx.x;
    if (tid < 4) hcnt[tid] = 0;
    __syncthreads();
    int t = blockIdx.x * 256 + tid;
    int e = mask[t] & 3;
    atomicAdd(&hcnt[e], 1);
    __syncthreads();
    if (tid < 4) { hb[tid] = atomicAdd(&counts[tid], hcnt[tid]); hpos[tid] = 0; }
    __syncthreads();
    int p = atomicAdd(&hpos[e], 1);
    list[e * T_TOK + hb[e] + p] = t;
}

// Fused gather + weight-convert (one dispatch instead of two):
// blockIdx.y 0..3: xc[e][i,:d_in] = bf16(x[list[e][i],:d_in])   (needs build)
// blockIdx.y 4   : w1bf/w2bf = bf16(w1/w2)                      (independent)
__global__ void k_xgc(const float* __restrict__ x, const int* __restrict__ counts,
                      const int* __restrict__ list, short* __restrict__ xc,
                      const float* __restrict__ w1, const float* __restrict__ w2,
                      short* __restrict__ w1bf, short* __restrict__ w2bf) {
    if (blockIdx.y == 4) {
        for (size_t elem = ((size_t)blockIdx.x * 256 + threadIdx.x) * 8;
             elem < (size_t)(W1N + W2N); elem += (size_t)gridDim.x * 256 * 8) {
            if (elem < (size_t)W1N) {
                conv8(w1 + elem, w1bf + elem);
            } else {
                size_t o = elem - W1N; conv8(w2 + o, w2bf + o);
            }
        }
        return;
    }
    const int e = blockIdx.y;
    const int d_in = 128 << e;
    const int cnt = counts[e];
    unsigned long long hbD, xb;
    bases_for(counts, e, &hbD, &xb);
    const size_t nel = (size_t)cnt * d_in;
    const int* lst = list + e * T_TOK;
    short* dst = xc + xb;
    for (size_t idx = ((size_t)blockIdx.x * 256 + threadIdx.x) * 8; idx < nel;
         idx += (size_t)gridDim.x * 256 * 8) {
        int row = (int)(idx >> (7 + e));
        int col = (int)(idx & (d_in - 1));
        int tok = lst[row];
        conv8(x + (size_t)tok * DMODEL + col, dst + idx);
    }
}

// ---------------------------------------------------------------------------
// Pass 1: h = gelu(xc @ W1[:d_hid, :d_in]^T + b1)  (bf16, compact rows)
// R13-LOCKED (best, ~80us): 128m x 128n tile, 512 threads (8 waves), per-wave
// shape = proven 32m x 64n / acc 2x4 / 16 MFMA per barrier. Single 32KB LDS,
// 2-barrier K-loop, XCD panel map. Supply: e3 = 128 blocks/XCD = 4/CU.
// Tile-geometry space fully bracketed: 64x128=105, 128x128/256t=125-168,
// 256x128/1024t=102, 128x256/512t=105 us -> this config is the optimum.
// ---------------------------------------------------------------------------
__global__ __launch_bounds__(512) void k_pass1(
    const short* __restrict__ xc, const short* __restrict__ w1bf,
    const float* __restrict__ b1, const int* __restrict__ counts,
    short* __restrict__ hbuf)
{
    const int d = blockIdx.x;        // 0..2047
    const int xcd = d & 7;
    const int slot = d >> 3;         // 0..255
    const int g = slot >> 5;         // panel group 0..7
    const int bx = slot & 31;        // m-block within panel
    int e, nt;
    if (g < 4)       { e = 3; nt = xcd * 4 + g; }
    else if (g < 6)  { e = 2; nt = xcd * 2 + (g - 4); }
    else if (g == 6) { e = 1; nt = xcd; }
    else             { if (xcd >= 4) return; e = 0; nt = xcd; }
    const int d_in = 128 << e;
    const int d_hid = d_in * 4;
    const int n0 = nt * 128;
    const int cnt = counts[e];
    unsigned long long hb, xb;
    bases_for(counts, e, &hb, &xb);
    const short* xe = xc + xb;

    __shared__ short Ab[128 * 64];   // 16KB
    __shared__ short Bb[128 * 64];   // 16KB

    const int tid = threadIdx.x;
    const int lane = tid & 63;
    const int w = tid >> 6;          // 0..7
    const int l3 = lane >> 3;        // 0..7
    const int ch = lane & 7;
    const int wm = (w & 3) * 32;     // 4-way m-split over 128 rows
    const int wn = (w >> 2) * 64;    // 2-way n-split over 128 cols

    for (int m0 = bx * 128; m0 < cnt; m0 += 32 * 128) {
        // A staging rows for this thread's 2 rounds (clamped)
        int rA[2];
#pragma unroll
        for (int j = 0; j < 2; ++j) {
            int rr = m0 + j * 64 + w * 8 + l3;
            rA[j] = (rr >= cnt) ? (cnt - 1) : rr;
        }

        f32x4 acc[2][4];
#pragma unroll
        for (int i = 0; i < 2; ++i)
#pragma unroll
            for (int j = 0; j < 4; ++j)
                acc[i][j] = (f32x4){0.f, 0.f, 0.f, 0.f};

        for (int k0 = 0; k0 < d_in; k0 += 64) {
#pragma unroll
            for (int j = 0; j < 2; ++j) {
                int r = j * 64 + w * 8 + l3;
                gl_lds16(xe + (size_t)rA[j] * d_in + k0 + ((ch ^ (r & 7)) << 3),
                         &Ab[(j * 64 + w * 8) * 64]);
            }
#pragma unroll
            for (int j = 0; j < 2; ++j) {
                int r = j * 64 + w * 8 + l3;
                gl_lds16(w1bf + (size_t)(n0 + r) * DMODEL + k0 + ((ch ^ (r & 7)) << 3),
                         &Bb[(j * 64 + w * 8) * 64]);
            }
            __syncthreads();
#pragma unroll
            for (int kk = 0; kk < 2; ++kk) {
                short8_t af[2], bfr[4];
                const int q = (lane >> 4) + kk * 4;
#pragma unroll
                for (int mt = 0; mt < 2; ++mt) {
                    int row = wm + mt * 16 + (lane & 15);
                    af[mt] = *(const short8_t*)&Ab[((row << 3) | (q ^ (row & 7))) << 3];
                }
#pragma unroll
                for (int ntn = 0; ntn < 4; ++ntn) {
                    int row = wn + ntn * 16 + (lane & 15);
                    bfr[ntn] = *(const short8_t*)&Bb[((row << 3) | (q ^ (row & 7))) << 3];
                }
#pragma unroll
                for (int mt = 0; mt < 2; ++mt)
#pragma unroll
                    for (int ntn = 0; ntn < 4; ++ntn)
                        acc[mt][ntn] = __builtin_amdgcn_mfma_f32_16x16x32_bf16(
                            af[mt], bfr[ntn], acc[mt][ntn], 0, 0, 0);
            }
            __syncthreads();
        }

        const int cl = lane & 15;
        const int qr = lane >> 4;
#pragma unroll
        for (int ntn = 0; ntn < 4; ++ntn) {
            int col = n0 + wn + ntn * 16 + cl;
            float bias = b1[col];
#pragma unroll
            for (int mt = 0; mt < 2; ++mt) {
#pragma unroll
                for (int r = 0; r < 4; ++r) {
                    int row = wm + mt * 16 + qr * 4 + r;
                    if (m0 + row < cnt) {
                        float v = acc[mt][ntn][r] + bias;
                        hbuf[hb + (unsigned long long)(m0 + row) * d_hid + col] =
                            f2bf(gelu_fast(v));
                    }
                }
            }
        }
    }
}

// ---------------------------------------------------------------------------
// Pass 2: y[tok, :d_out] = h @ W2[:d_out, :d_hid]^T + b2  (scatter, fp32)
// R13-LOCKED (banked best, 92us): 128m x 128n, 512 thr, counted-vmcnt(4)
// dbuf 64KB, XCD PANEL map. Both passes sit at the measured ~6.5 TB/s
// staged-byte wall; byte-reduction trades occupancy at a net loss (5x
// falsified), latency/TLP/locality moves at constant bytes are null.
//   g0: e3 panel nt=xcd | g1: xcd0-3 e2 | xcd4,5 e1 | xcd6 e0 | xcd7 idle
//   g2: flattened zero-fill of y pad cols (128-row chunks, 512 workers)
// ---------------------------------------------------------------------------
__global__ __launch_bounds__(512) void k_pass2(
    const short* __restrict__ hbuf, const short* __restrict__ w2bf,
    const float* __restrict__ b2, const int* __restrict__ counts,
    const int* __restrict__ list, float* __restrict__ y)
{
    const int d = blockIdx.x;        // 0..1535
    const int xcd = d & 7;
    const int slot = d >> 3;         // 0..191
    const int g = slot >> 6;         // 0..2
    const int bx = slot & 63;
    if (g == 2) {
        // flattened zero-fill of pad region: 128-row chunks
        const int z = xcd * 64 + bx;              // 0..511
        const int ch2 = (counts[2] + 127) >> 7, ch1 = (counts[1] + 127) >> 7,
                  ch0 = (counts[0] + 127) >> 7;
        const int n2 = ch2 * 4, n1 = ch1 * 6, n0c = ch0 * 7;
        const int rt = threadIdx.x >> 2;          // row-in-chunk 0..127
        const int cq = (threadIdx.x & 3) * 32;    // col quarter
        const float4 z4 = (float4){0.f, 0.f, 0.f, 0.f};
        for (int c = z; c < n2 + n1 + n0c; c += 512) {
            int e, nt, mi, cc = c;
            if (cc < n2)            { e = 2; nt = 4 + cc / ch2; mi = cc % ch2; }
            else { cc -= n2;
                if (cc < n1)        { e = 1; nt = 2 + cc / ch1; mi = cc % ch1; }
                else { cc -= n1;      e = 0; nt = 1 + cc / ch0; mi = cc % ch0; } }
            const int cnt = counts[e];
            int row = mi * 128 + rt;
            if (row < cnt) {
                float* dst = y + (size_t)list[e * T_TOK + row] * OUTD + nt * 128 + cq;
#pragma unroll
                for (int i = 0; i < 8; ++i) *(float4*)(dst + i * 4) = z4;
            }
        }
        return;
    }
    int e, nt;
    if (g == 0) { e = 3; nt = xcd; }
    else {
        if (xcd < 4)       { e = 2; nt = xcd; }
        else if (xcd < 6)  { e = 1; nt = xcd - 4; }
        else if (xcd == 6) { e = 0; nt = 0; }
        else return;
    }
    const int d_in = 128 << e;
    const int d_hid = d_in * 4;
    const int n0 = nt * 128;
    const int cnt = counts[e];
    const int* lst = list + e * T_TOK;
    unsigned long long hb, xb;
    bases_for(counts, e, &hb, &xb);

    __shared__ short Ab[2 * 128 * 64];   // 32KB
    __shared__ short Bb[2 * 128 * 64];   // 32KB

    const int tid = threadIdx.x;
    const int lane = tid & 63;
    const int w = tid >> 6;          // 0..7
    const int l3 = lane >> 3;
    const int ch = lane & 7;
    const int wm = (w & 3) * 32;     // 4-way m-split over 128 rows
    const int wn = (w >> 2) * 64;    // 2-way n-split over 128 cols

#define P2_STAGE(kn, b) do {                                                   \
    _Pragma("unroll") for (int j = 0; j < 2; ++j) {                            \
        int r = j * 64 + w * 8 + l3;                                           \
        gl_lds16(hbuf + hb + (size_t)rA[j] * d_hid + (kn) + ((ch ^ (r & 7)) << 3), \
                 &Ab[(b) * 8192 + (j * 64 + w * 8) * 64]); }                   \
    _Pragma("unroll") for (int j = 0; j < 2; ++j) {                            \
        int r = j * 64 + w * 8 + l3;                                           \
        gl_lds16(w2bf + (size_t)(n0 + r) * HDIM + (kn) + ((ch ^ (r & 7)) << 3), \
                 &Bb[(b) * 8192 + (j * 64 + w * 8) * 64]); }                   \
} while (0)

    for (int m0 = bx * 128; m0 < cnt; m0 += 64 * 128) {
        int rA[2];
#pragma unroll
        for (int j = 0; j < 2; ++j) {
            int rr = m0 + j * 64 + w * 8 + l3;
            rA[j] = (rr >= cnt) ? (cnt - 1) : rr;
        }

        f32x4 acc[2][4];
#pragma unroll
        for (int i = 0; i < 2; ++i)
#pragma unroll
            for (int j = 0; j < 4; ++j)
                acc[i][j] = (f32x4){0.f, 0.f, 0.f, 0.f};

        const int ks = d_hid >> 6;       // 8/16/32/64 (always even)
        P2_STAGE(0, 0);                  // prologue: kt=0 -> buf0
        for (int kt = 0; kt < ks; ++kt) {
            const int p = kt & 1;
            __builtin_amdgcn_s_barrier();                    // B1
            if (kt + 1 < ks) {
                P2_STAGE((kt + 1) << 6, 1 - p);
                asm volatile("s_waitcnt vmcnt(4)" ::: "memory");
            } else {
                asm volatile("s_waitcnt vmcnt(0)" ::: "memory");
            }
            __builtin_amdgcn_s_barrier();                    // B2
            const short* Ap = &Ab[p * 8192];
            const short* Bp = &Bb[p * 8192];
#pragma unroll
            for (int kk = 0; kk < 2; ++kk) {
                short8_t af[2], bfr[4];
                const int q = (lane >> 4) + kk * 4;
#pragma unroll
                for (int mt = 0; mt < 2; ++mt) {
                    int row = wm + mt * 16 + (lane & 15);
                    af[mt] = *(const short8_t*)&Ap[((row << 3) | (q ^ (row & 7))) << 3];
                }
#pragma unroll
                for (int ntn = 0; ntn < 4; ++ntn) {
                    int row = wn + ntn * 16 + (lane & 15);
                    bfr[ntn] = *(const short8_t*)&Bp[((row << 3) | (q ^ (row & 7))) << 3];
                }
#pragma unroll
                for (int mt = 0; mt < 2; ++mt)
#pragma unroll
                    for (int ntn = 0; ntn < 4; ++ntn)
                        acc[mt][ntn] = __builtin_amdgcn_mfma_f32_16x16x32_bf16(
                            af[mt], bfr[ntn], acc[mt][ntn], 0, 0, 0);
            }
        }

        const int cl = lane & 15;
        const int qr = lane >> 4;
#pragma unroll
        for (int ntn = 0; ntn < 4; ++ntn) {
            int col = n0 + wn + ntn * 16 + cl;
            float bias = b2[col];
#pragma unroll
            for (int mt = 0; mt < 2; ++mt) {
#pragma unroll
                for (int r = 0; r < 4; ++r) {
                    int row = wm + mt * 16 + qr * 4 + r;
                    if (m0 + row < cnt) {
                        int tok = lst[m0 + row];
                        y[(size_t)tok * OUTD + col] = acc[mt][ntn][r] + bias;
                    }
                }
            }
        }
    }
#undef P2_STAGE
}

extern "C" void kernel_launch(void* const* d_in, const int* in_sizes, int n_in,
                              void* d_out, int out_size, void* d_ws, size_t ws_size,
                              hipStream_t stream) {
    const float* x  = (const float*)d_in[0];
    const int* mask = (const int*)d_in[1];
    const float* w1 = (const float*)d_in[2];
    const float* b1 = (const float*)d_in[3];
    const float* w2 = (const float*)d_in[4];
    const float* b2 = (const float*)d_in[5];
    float* y = (float*)d_out;

    char* ws = (char*)d_ws;
    int* counts = (int*)(ws + WS_COUNTS_OFF);
    int* list = (int*)(ws + WS_LIST_OFF);
    short* xc   = (short*)(ws + WS_XC_OFF);
    short* w1bf = (short*)(ws + WS_W1BF_OFF);
    short* w2bf = (short*)(ws + WS_W2BF_OFF);
    short* hbuf = (short*)(ws + WS_HBUF_OFF);

    hipMemsetAsync(counts, 0, 4 * sizeof(int), stream);
    k_build<<<T_TOK / 256, 256, 0, stream>>>(mask, counts, list);
    k_xgc<<<dim3(256, 5), 256, 0, stream>>>(x, counts, list, xc, w1, w2, w1bf, w2bf);
    k_pass1<<<2048, 512, 0, stream>>>(xc, w1bf, b1, counts, hbuf);
    k_pass2<<<1536, 512, 0, stream>>>(hbuf, w2bf, b2, counts, list, y);
}